// Round 3
// baseline (477.676 us; speedup 1.0000x reference)
//
#include <hip/hip_runtime.h>

#define G      1024
#define NNODES 65536
#define NEDGES 262144
#define D      256
#define DIN    768
#define DHID   512
#define DOUT   256

__device__ __forceinline__ int lower_bound(const int* __restrict__ a, int n, int key) {
    int lo = 0, hi = n;
    while (lo < hi) {
        const int mid = (lo + hi) >> 1;
        if (a[mid] < key) lo = mid + 1; else hi = mid;
    }
    return lo;
}

// One block per graph. Binary-search the sorted id arrays for this graph's
// contiguous row ranges, stream-sum them (no atomics, no per-row id checks),
// LDS-reduce across the 4 waves, write collected[g] = [edge_agg|node_agg|globals].
__global__ __launch_bounds__(256) void fused_agg(
        const float4* __restrict__ nodes,
        const float4* __restrict__ edges,
        const float4* __restrict__ globals_,
        const int* __restrict__ nids,
        const int* __restrict__ eids,
        float* __restrict__ collected) {
    const int g    = blockIdx.x;
    const int lane = threadIdx.x & 63;
    const int wave = threadIdx.x >> 6;

    const int es = lower_bound(eids, NEDGES, g);
    const int ee = lower_bound(eids, NEDGES, g + 1);
    const int ns = lower_bound(nids, NNODES, g);
    const int ne = lower_bound(nids, NNODES, g + 1);

    float4 acc_e = {0.f, 0.f, 0.f, 0.f};
    {   // edges: waves stride rows by 4; 4 rows in flight per wave (4 KiB MLP)
        int r = es + wave;
        for (; r + 12 < ee; r += 16) {
            const float4 v0 = edges[(size_t)(r +  0) * (D / 4) + lane];
            const float4 v1 = edges[(size_t)(r +  4) * (D / 4) + lane];
            const float4 v2 = edges[(size_t)(r +  8) * (D / 4) + lane];
            const float4 v3 = edges[(size_t)(r + 12) * (D / 4) + lane];
            acc_e.x += (v0.x + v1.x) + (v2.x + v3.x);
            acc_e.y += (v0.y + v1.y) + (v2.y + v3.y);
            acc_e.z += (v0.z + v1.z) + (v2.z + v3.z);
            acc_e.w += (v0.w + v1.w) + (v2.w + v3.w);
        }
        for (; r < ee; r += 4) {
            const float4 v = edges[(size_t)r * (D / 4) + lane];
            acc_e.x += v.x; acc_e.y += v.y; acc_e.z += v.z; acc_e.w += v.w;
        }
    }

    float4 acc_n = {0.f, 0.f, 0.f, 0.f};
    {   // nodes
        int r = ns + wave;
        for (; r + 12 < ne; r += 16) {
            const float4 v0 = nodes[(size_t)(r +  0) * (D / 4) + lane];
            const float4 v1 = nodes[(size_t)(r +  4) * (D / 4) + lane];
            const float4 v2 = nodes[(size_t)(r +  8) * (D / 4) + lane];
            const float4 v3 = nodes[(size_t)(r + 12) * (D / 4) + lane];
            acc_n.x += (v0.x + v1.x) + (v2.x + v3.x);
            acc_n.y += (v0.y + v1.y) + (v2.y + v3.y);
            acc_n.z += (v0.z + v1.z) + (v2.z + v3.z);
            acc_n.w += (v0.w + v1.w) + (v2.w + v3.w);
        }
        for (; r < ne; r += 4) {
            const float4 v = nodes[(size_t)r * (D / 4) + lane];
            acc_n.x += v.x; acc_n.y += v.y; acc_n.z += v.z; acc_n.w += v.w;
        }
    }

    __shared__ __align__(16) float se[4][D];
    __shared__ __align__(16) float sn[4][D];
    *(float4*)&se[wave][lane * 4] = acc_e;   // b128 writes: 2-way bank alias, free (m136)
    *(float4*)&sn[wave][lane * 4] = acc_n;
    __syncthreads();

    const int t = threadIdx.x;   // 0..255 = output column
    const float ev = (se[0][t] + se[1][t]) + (se[2][t] + se[3][t]);
    const float nv = (sn[0][t] + sn[1][t]) + (sn[2][t] + sn[3][t]);
    float* row = collected + (size_t)g * DIN;
    row[t]           = ev;
    row[D + t]       = nv;
    row[2 * D + t]   = ((const float*)globals_)[(size_t)g * D + t];
}

// fp32 tiled GEMM: C[M,N] = act(A[M,K] @ B[K,N] + bias), tile 32x64, TK=32,
// 256 threads (16x16), micro-tile 2x4. As padded +1; Bs b128 reads 2-way
// aliased (free, m136).
template <int TM, int TN, int TK>
__global__ __launch_bounds__(256) void gemm_bias_act(
        const float* __restrict__ A, const float* __restrict__ B,
        const float* __restrict__ bias, float* __restrict__ C,
        int M, int N, int K, int relu) {
    __shared__ float As[TM][TK + 1];
    __shared__ __align__(16) float Bs[TK][TN];

    const int tid = threadIdx.x;
    const int tx = tid & 15;   // 4 cols each
    const int ty = tid >> 4;   // 2 rows each
    const int m0 = blockIdx.y * TM;
    const int n0 = blockIdx.x * TN;

    float4 acc0 = {0.f, 0.f, 0.f, 0.f};
    float4 acc1 = {0.f, 0.f, 0.f, 0.f};

    for (int kt = 0; kt < K; kt += TK) {
        {   // stage A tile: 32x32 floats, one float4/thread
            const int r = tid >> 3;
            const int c = (tid & 7) * 4;
            const float4 a4 = *(const float4*)&A[(size_t)(m0 + r) * K + kt + c];
            As[r][c] = a4.x; As[r][c + 1] = a4.y; As[r][c + 2] = a4.z; As[r][c + 3] = a4.w;
        }
        {   // stage B tile: 32x64 floats, two float4/thread
            const int r = tid >> 3;
            const int c = (tid & 7) * 8;
            *(float4*)&Bs[r][c]     = *(const float4*)&B[(size_t)(kt + r) * N + n0 + c];
            *(float4*)&Bs[r][c + 4] = *(const float4*)&B[(size_t)(kt + r) * N + n0 + c + 4];
        }
        __syncthreads();
#pragma unroll
        for (int k = 0; k < TK; ++k) {
            const float a0 = As[ty * 2 + 0][k];
            const float a1 = As[ty * 2 + 1][k];
            const float4 bv = *(const float4*)&Bs[k][tx * 4];
            acc0.x += a0 * bv.x; acc0.y += a0 * bv.y;
            acc0.z += a0 * bv.z; acc0.w += a0 * bv.w;
            acc1.x += a1 * bv.x; acc1.y += a1 * bv.y;
            acc1.z += a1 * bv.z; acc1.w += a1 * bv.w;
        }
        __syncthreads();
    }

    const int col = n0 + tx * 4;
    const int row = m0 + ty * 2;
    const float4 bv = *(const float4*)&bias[col];
    float4 o0, o1;
    o0.x = acc0.x + bv.x; o0.y = acc0.y + bv.y; o0.z = acc0.z + bv.z; o0.w = acc0.w + bv.w;
    o1.x = acc1.x + bv.x; o1.y = acc1.y + bv.y; o1.z = acc1.z + bv.z; o1.w = acc1.w + bv.w;
    if (relu) {
        o0.x = fmaxf(o0.x, 0.f); o0.y = fmaxf(o0.y, 0.f);
        o0.z = fmaxf(o0.z, 0.f); o0.w = fmaxf(o0.w, 0.f);
        o1.x = fmaxf(o1.x, 0.f); o1.y = fmaxf(o1.y, 0.f);
        o1.z = fmaxf(o1.z, 0.f); o1.w = fmaxf(o1.w, 0.f);
    }
    *(float4*)&C[(size_t)row * N + col] = o0;
    *(float4*)&C[(size_t)(row + 1) * N + col] = o1;
}

extern "C" void kernel_launch(void* const* d_in, const int* in_sizes, int n_in,
                              void* d_out, int out_size, void* d_ws, size_t ws_size,
                              hipStream_t stream) {
    const float* nodes    = (const float*)d_in[0];
    const float* edges    = (const float*)d_in[1];
    const float* globals_ = (const float*)d_in[2];
    const int*   nids     = (const int*)d_in[3];
    const int*   eids     = (const int*)d_in[4];
    const float* W1       = (const float*)d_in[5];
    const float* b1       = (const float*)d_in[6];
    const float* W2       = (const float*)d_in[7];
    const float* b2       = (const float*)d_in[8];
    float* out = (float*)d_out;

    float* collected = (float*)d_ws;                 // [G, DIN]  (3 MB), fully written
    float* h         = collected + (size_t)G * DIN;  // [G, DHID] (2 MB), fully written

    fused_agg<<<G, 256, 0, stream>>>(
        (const float4*)nodes, (const float4*)edges, (const float4*)globals_,
        nids, eids, collected);

    gemm_bias_act<32, 64, 32><<<dim3(DHID / 64, G / 32), 256, 0, stream>>>(
        collected, W1, b1, h, G, DHID, DIN, 1);

    gemm_bias_act<32, 64, 32><<<dim3(DOUT / 64, G / 32), 256, 0, stream>>>(
        h, W2, b2, out, G, DOUT, DHID, 0);
}

// Round 4
// 465.176 us; speedup vs baseline: 1.0269x; 1.0269x over previous
//
#include <hip/hip_runtime.h>

#define G      1024
#define NNODES 65536
#define NEDGES 262144
#define D      256
#define DIN    768
#define DHID   512
#define DOUT   256

__device__ __forceinline__ int lower_bound(const int* __restrict__ a, int n, int key) {
    int lo = 0, hi = n;
    while (lo < hi) {
        const int mid = (lo + hi) >> 1;
        if (a[mid] < key) lo = mid + 1; else hi = mid;
    }
    return lo;
}

// One block per graph. Binary-search the sorted id arrays for this graph's
// contiguous row ranges, stream-sum with 8 float4 loads in flight per wave
// (8 KiB MLP), LDS-reduce across the 4 waves, write collected[g].
__global__ __launch_bounds__(256) void fused_agg(
        const float4* __restrict__ nodes,
        const float4* __restrict__ edges,
        const float4* __restrict__ globals_,
        const int* __restrict__ nids,
        const int* __restrict__ eids,
        float* __restrict__ collected) {
    const int g    = blockIdx.x;
    const int lane = threadIdx.x & 63;
    const int wave = threadIdx.x >> 6;

    const int es = lower_bound(eids, NEDGES, g);
    const int ee = lower_bound(eids, NEDGES, g + 1);
    const int ns = lower_bound(nids, NNODES, g);
    const int ne = lower_bound(nids, NNODES, g + 1);

    float4 acc_e = {0.f, 0.f, 0.f, 0.f};
    {
        int r = es + wave;
        for (; r + 28 < ee; r += 32) {      // 8 rows in flight, waves interleave by 4
            const float4 v0 = edges[(size_t)(r +  0) * (D / 4) + lane];
            const float4 v1 = edges[(size_t)(r +  4) * (D / 4) + lane];
            const float4 v2 = edges[(size_t)(r +  8) * (D / 4) + lane];
            const float4 v3 = edges[(size_t)(r + 12) * (D / 4) + lane];
            const float4 v4 = edges[(size_t)(r + 16) * (D / 4) + lane];
            const float4 v5 = edges[(size_t)(r + 20) * (D / 4) + lane];
            const float4 v6 = edges[(size_t)(r + 24) * (D / 4) + lane];
            const float4 v7 = edges[(size_t)(r + 28) * (D / 4) + lane];
            acc_e.x += ((v0.x + v1.x) + (v2.x + v3.x)) + ((v4.x + v5.x) + (v6.x + v7.x));
            acc_e.y += ((v0.y + v1.y) + (v2.y + v3.y)) + ((v4.y + v5.y) + (v6.y + v7.y));
            acc_e.z += ((v0.z + v1.z) + (v2.z + v3.z)) + ((v4.z + v5.z) + (v6.z + v7.z));
            acc_e.w += ((v0.w + v1.w) + (v2.w + v3.w)) + ((v4.w + v5.w) + (v6.w + v7.w));
        }
        for (; r < ee; r += 4) {
            const float4 v = edges[(size_t)r * (D / 4) + lane];
            acc_e.x += v.x; acc_e.y += v.y; acc_e.z += v.z; acc_e.w += v.w;
        }
    }

    float4 acc_n = {0.f, 0.f, 0.f, 0.f};
    {
        int r = ns + wave;
        for (; r + 28 < ne; r += 32) {
            const float4 v0 = nodes[(size_t)(r +  0) * (D / 4) + lane];
            const float4 v1 = nodes[(size_t)(r +  4) * (D / 4) + lane];
            const float4 v2 = nodes[(size_t)(r +  8) * (D / 4) + lane];
            const float4 v3 = nodes[(size_t)(r + 12) * (D / 4) + lane];
            const float4 v4 = nodes[(size_t)(r + 16) * (D / 4) + lane];
            const float4 v5 = nodes[(size_t)(r + 20) * (D / 4) + lane];
            const float4 v6 = nodes[(size_t)(r + 24) * (D / 4) + lane];
            const float4 v7 = nodes[(size_t)(r + 28) * (D / 4) + lane];
            acc_n.x += ((v0.x + v1.x) + (v2.x + v3.x)) + ((v4.x + v5.x) + (v6.x + v7.x));
            acc_n.y += ((v0.y + v1.y) + (v2.y + v3.y)) + ((v4.y + v5.y) + (v6.y + v7.y));
            acc_n.z += ((v0.z + v1.z) + (v2.z + v3.z)) + ((v4.z + v5.z) + (v6.z + v7.z));
            acc_n.w += ((v0.w + v1.w) + (v2.w + v3.w)) + ((v4.w + v5.w) + (v6.w + v7.w));
        }
        for (; r < ne; r += 4) {
            const float4 v = nodes[(size_t)r * (D / 4) + lane];
            acc_n.x += v.x; acc_n.y += v.y; acc_n.z += v.z; acc_n.w += v.w;
        }
    }

    __shared__ __align__(16) float se[4][D];
    __shared__ __align__(16) float sn[4][D];
    *(float4*)&se[wave][lane * 4] = acc_e;
    *(float4*)&sn[wave][lane * 4] = acc_n;
    __syncthreads();

    const int t = threadIdx.x;   // output column
    const float ev = (se[0][t] + se[1][t]) + (se[2][t] + se[3][t]);
    const float nv = (sn[0][t] + sn[1][t]) + (sn[2][t] + sn[3][t]);
    float* row = collected + (size_t)g * DIN;
    row[t]         = ev;
    row[D + t]     = nv;
    row[2 * D + t] = ((const float*)globals_)[(size_t)g * D + t];
}

// fp32 GEMM, C[M,N]=act(A@B+bias): tile TMxTN=32x64, TK=32, 256 threads,
// micro 2x4. A stored k-major in LDS (pad +2 keeps b64 reads 8B-aligned).
// Register->LDS double buffering: tile k+1's global loads issue before the
// compute on tile k, one barrier per K-tile.
template <int TM, int TN, int TK>
__global__ __launch_bounds__(256) void gemm_bias_act(
        const float* __restrict__ A, const float* __restrict__ B,
        const float* __restrict__ bias, float* __restrict__ C,
        int M, int N, int K, int relu) {
    __shared__ float At[2][TK][TM + 2];            // k-major A
    __shared__ __align__(16) float Bs[2][TK][TN];

    const int tid = threadIdx.x;
    const int tx = tid & 15;          // 4 cols
    const int ty = tid >> 4;          // 2 rows
    const int m0 = blockIdx.y * TM;
    const int n0 = blockIdx.x * TN;

    const int ar = tid >> 3;          // A row       0..31
    const int ac = (tid & 7) * 4;     // A k-col     0,4,..,28
    const int br = tid >> 3;          // B k-row     0..31
    const int bc = (tid & 7) * 8;     // B col       0,8,..,56

    const float* Aptr = A + (size_t)(m0 + ar) * K + ac;
    const float* Bptr = B + (size_t)br * N + n0 + bc;

    {   // preload tile 0
        const float4 a4  = *(const float4*)Aptr;
        const float4 b40 = *(const float4*)Bptr;
        const float4 b41 = *(const float4*)(Bptr + 4);
        At[0][ac + 0][ar] = a4.x; At[0][ac + 1][ar] = a4.y;
        At[0][ac + 2][ar] = a4.z; At[0][ac + 3][ar] = a4.w;
        *(float4*)&Bs[0][br][bc]     = b40;
        *(float4*)&Bs[0][br][bc + 4] = b41;
    }
    __syncthreads();

    float4 acc0 = {0.f, 0.f, 0.f, 0.f};
    float4 acc1 = {0.f, 0.f, 0.f, 0.f};
    int buf = 0;

    for (int kt = 0; kt < K; kt += TK) {
        const bool has_next = (kt + TK) < K;
        float4 na, nb0, nb1;
        if (has_next) {                            // issue next tile's loads NOW
            na  = *(const float4*)(Aptr + kt + TK);
            nb0 = *(const float4*)(Bptr + (size_t)(kt + TK) * N);
            nb1 = *(const float4*)(Bptr + (size_t)(kt + TK) * N + 4);
        }
#pragma unroll
        for (int k = 0; k < TK; ++k) {
            const float2 a2 = *(const float2*)&At[buf][k][ty * 2];   // broadcast b64
            const float4 bv = *(const float4*)&Bs[buf][k][tx * 4];   // 2-way alias, free
            acc0.x += a2.x * bv.x; acc0.y += a2.x * bv.y;
            acc0.z += a2.x * bv.z; acc0.w += a2.x * bv.w;
            acc1.x += a2.y * bv.x; acc1.y += a2.y * bv.y;
            acc1.z += a2.y * bv.z; acc1.w += a2.y * bv.w;
        }
        if (has_next) {
            const int nb = buf ^ 1;
            At[nb][ac + 0][ar] = na.x; At[nb][ac + 1][ar] = na.y;
            At[nb][ac + 2][ar] = na.z; At[nb][ac + 3][ar] = na.w;
            *(float4*)&Bs[nb][br][bc]     = nb0;
            *(float4*)&Bs[nb][br][bc + 4] = nb1;
            __syncthreads();
            buf = nb;
        }
    }

    const int col = n0 + tx * 4;
    const int row = m0 + ty * 2;
    const float4 bv = *(const float4*)&bias[col];
    float4 o0, o1;
    o0.x = acc0.x + bv.x; o0.y = acc0.y + bv.y; o0.z = acc0.z + bv.z; o0.w = acc0.w + bv.w;
    o1.x = acc1.x + bv.x; o1.y = acc1.y + bv.y; o1.z = acc1.z + bv.z; o1.w = acc1.w + bv.w;
    if (relu) {
        o0.x = fmaxf(o0.x, 0.f); o0.y = fmaxf(o0.y, 0.f);
        o0.z = fmaxf(o0.z, 0.f); o0.w = fmaxf(o0.w, 0.f);
        o1.x = fmaxf(o1.x, 0.f); o1.y = fmaxf(o1.y, 0.f);
        o1.z = fmaxf(o1.z, 0.f); o1.w = fmaxf(o1.w, 0.f);
    }
    *(float4*)&C[(size_t)row * N + col] = o0;
    *(float4*)&C[(size_t)(row + 1) * N + col] = o1;
}

extern "C" void kernel_launch(void* const* d_in, const int* in_sizes, int n_in,
                              void* d_out, int out_size, void* d_ws, size_t ws_size,
                              hipStream_t stream) {
    const float* nodes    = (const float*)d_in[0];
    const float* edges    = (const float*)d_in[1];
    const float* globals_ = (const float*)d_in[2];
    const int*   nids     = (const int*)d_in[3];
    const int*   eids     = (const int*)d_in[4];
    const float* W1       = (const float*)d_in[5];
    const float* b1       = (const float*)d_in[6];
    const float* W2       = (const float*)d_in[7];
    const float* b2       = (const float*)d_in[8];
    float* out = (float*)d_out;

    float* collected = (float*)d_ws;                 // [G, DIN]  (3 MB), fully written
    float* h         = collected + (size_t)G * DIN;  // [G, DHID] (2 MB), fully written

    fused_agg<<<G, 256, 0, stream>>>(
        (const float4*)nodes, (const float4*)edges, (const float4*)globals_,
        nids, eids, collected);

    gemm_bias_act<32, 64, 32><<<dim3(DHID / 64, G / 32), 256, 0, stream>>>(
        collected, W1, b1, h, G, DHID, DIN, 1);

    gemm_bias_act<32, 64, 32><<<dim3(DOUT / 64, G / 32), 256, 0, stream>>>(
        h, W2, b2, out, G, DOUT, DHID, 0);
}